// Round 3
// baseline (7676.922 us; speedup 1.0000x reference)
//
#include <hip/hip_runtime.h>
#include <cstdint>
#include <cstddef>

using u32 = unsigned int;
typedef _Float16 f16;
typedef _Float16 f16x2 __attribute__((ext_vector_type(2)));

// ---------- helpers ----------
__device__ __forceinline__ u32 pack2h(float a, float b) {
  f16x2 p; p.x = (f16)a; p.y = (f16)b;
  return __builtin_bit_cast(u32, p);
}
__device__ __forceinline__ unsigned short h_bits(float x) {
  f16 h = (f16)x; return __builtin_bit_cast(unsigned short, h);
}
// acc += dot2(f16x2 a, f16x2 b)  -- v_dot2_f32_f16
__device__ __forceinline__ void dot2(float& acc, u32 a, u32 b) {
#if __has_builtin(__builtin_amdgcn_fdot2)
  acc = __builtin_amdgcn_fdot2(__builtin_bit_cast(f16x2, a),
                               __builtin_bit_cast(f16x2, b), acc, false);
#else
  f16x2 x = __builtin_bit_cast(f16x2, a), y = __builtin_bit_cast(f16x2, b);
  acc = fmaf((float)x.y, (float)y.y, fmaf((float)x.x, (float)y.x, acc));
#endif
}
__device__ __forceinline__ float sigm(float x) { return 1.f / (1.f + __expf(-x)); }

// ---------- sizes ----------
#define BB 128
#define TT 1024
#define DD 128
#define UU 256
#define MM 64
#define N_UP    131072   // U packed [kq][col][kd]  (col = gate*256+u, kd = 32 pair-dwords)
#define N_WCX   65536    // W_cat packed [col][kd0..63]
#define N_WMP   8192     // W_mem packed [u][md0..31]
#define N_UMP   8192     // U_mem packed [q][m][kd0..31]
#define N_BIAS  1024     // f32 bias

// ---------- pack: f32 weights -> f16-pair layouts ----------
__global__ void pack_kernel(const float* Wi, const float* Wf, const float* Wc, const float* Wo,
                            const float* Ui, const float* Uf, const float* Uc, const float* Uo,
                            const float* Wmem, const float* Umem,
                            const float* bi, const float* bfv, const float* bc, const float* bo,
                            u32* Up, u32* Wcx, u32* Wmp, u32* Ump, float* bias) {
  int idx = blockIdx.x * blockDim.x + threadIdx.x;
  const int total = N_UP + N_WCX + N_WMP + N_UMP + N_BIAS;
  for (int i = idx; i < total; i += gridDim.x * blockDim.x) {
    if (i < N_UP) {
      int kq = i >> 15, rem = i & 32767, col = rem >> 5, kd = rem & 31;
      int g = col >> 8, u = col & 255, k0 = kq * 64 + kd * 2;
      const float* Ug = (g == 0 ? Ui : g == 1 ? Uf : g == 2 ? Uc : Uo);
      Up[i] = pack2h(Ug[k0 * 256 + u], Ug[(k0 + 1) * 256 + u]);
    } else if (i < N_UP + N_WCX) {
      int j = i - N_UP;
      int col = j >> 6, kd = j & 63, g = col >> 8, u = col & 255, k0 = kd * 2;
      const float* Wg = (g == 0 ? Wi : g == 1 ? Wf : g == 2 ? Wc : Wo);
      Wcx[j] = pack2h(Wg[k0 * 256 + u], Wg[(k0 + 1) * 256 + u]);
    } else if (i < N_UP + N_WCX + N_WMP) {
      int j = i - (N_UP + N_WCX);
      int u = j >> 5, md = j & 31, m0 = md * 2;
      Wmp[j] = pack2h(Wmem[m0 * 256 + u], Wmem[(m0 + 1) * 256 + u]);
    } else if (i < N_UP + N_WCX + N_WMP + N_UMP) {
      int j = i - (N_UP + N_WCX + N_WMP);
      int q = j >> 11, m = (j >> 5) & 63, kd = j & 31, k0 = q * 64 + kd * 2;
      Ump[j] = pack2h(Umem[k0 * 64 + m], Umem[(k0 + 1) * 64 + m]);
    } else {
      int j = i - (N_UP + N_WCX + N_WMP + N_UMP);
      int g = j >> 8;
      const float* bg = (g == 0 ? bi : g == 1 ? bfv : g == 2 ? bc : bo);
      bias[j] = bg[j & 255];
    }
  }
}

// ---------- x projection: X[ci][1024] = inp_row @ W_cat + bias (f32 out) ----------
// chunk rows = B*tlen; 64 rows/block (one batch row per block, tlen>=64); thread owns 2 cols.
__global__ __launch_bounds__(512) void xproj_kernel(const float* __restrict__ inp,
                                                    const u32* __restrict__ Wcx,
                                                    const float* __restrict__ bias,
                                                    float* __restrict__ X,
                                                    int t0, int tlen) {
  __shared__ u32 ilds[64][64];  // 64 rows x 64 f16-pair dwords
  const int t = threadIdx.x;
  const int blk = blockIdx.x;
  const int bpr = tlen >> 6;             // blocks per batch row
  const int r = blk / bpr;
  const int boff = blk - r * bpr;        // which 64-step slice
  const int ts0 = t0 + boff * 64;
  const float* ip = inp + ((size_t)r * TT + ts0) * DD;
  #pragma unroll
  for (int i = 0; i < 4; ++i) {
    int fi = t + i * 512;                // 2048 float4 = 64 rows x 128 f32
    float4 v = ((const float4*)ip)[fi];
    int row = fi >> 5, kd = (fi & 31) * 2;
    ilds[row][kd]     = pack2h(v.x, v.y);
    ilds[row][kd + 1] = pack2h(v.z, v.w);
  }
  __syncthreads();
  const int c0 = 2 * t, c1 = 2 * t + 1;
  uint4 wa4[16], wb4[16];
  const uint4* Wa = (const uint4*)(Wcx + (size_t)c0 * 64);
  const uint4* Wb = (const uint4*)(Wcx + (size_t)c1 * 64);
  #pragma unroll
  for (int i = 0; i < 16; ++i) { wa4[i] = Wa[i]; wb4[i] = Wb[i]; }
  const float ba = bias[c0], bb = bias[c1];
  const size_t cibase = (size_t)r * tlen + (size_t)boff * 64;
  for (int rl = 0; rl < 64; ++rl) {
    float a = ba, b = bb;
    #pragma unroll
    for (int c4 = 0; c4 < 16; ++c4) {
      uint4 hv = *(const uint4*)&ilds[rl][c4 * 4];  // broadcast
      dot2(a, wa4[c4].x, hv.x); dot2(a, wa4[c4].y, hv.y);
      dot2(a, wa4[c4].z, hv.z); dot2(a, wa4[c4].w, hv.w);
      dot2(b, wb4[c4].x, hv.x); dot2(b, wb4[c4].y, hv.y);
      dot2(b, wb4[c4].z, hv.z); dot2(b, wb4[c4].w, hv.w);
    }
    float2 st2; st2.x = a; st2.y = b;
    *(float2*)&X[(cibase + rl) * 1024 + c0] = st2;
  }
}

// ---------- recurrent kernel: 128 blocks (1/batch row) x 512 threads ----------
// thread t: kq = t>>7 (K-quarter, 64 h elems), l7 = t&127.
// gate columns l7+128j: j=0..6 in REGISTERS (224 dwords), j=7 in swizzled LDS.
// 147KB LDS -> 1 block/CU (8 waves, 2/SIMD) -> VGPR hard cap 256.
__global__ __launch_bounds__(512, 2) void rec_kernel(const u32* __restrict__ Up,
                                                     const u32* __restrict__ Wmp,
                                                     const u32* __restrict__ Ump,
                                                     const float* __restrict__ X,
                                                     float* __restrict__ out,
                                                     u32* __restrict__ st,
                                                     int t0, int tlen) {
  __shared__ u32 Ulds[4][128][32];   // 64KB  U gate overflow (j=7), XOR-swizzled
  __shared__ u32 Wml[256][32];       // 32KB  W_mem, swizzled
  __shared__ u32 Uml[4][64][32];     // 32KB  U_mem, swizzled
  __shared__ u32 hp[128];            // h as f16 pairs
  __shared__ u32 memp[32];           // mem as f16 pairs
  __shared__ float part[4][1024];    // 16KB gate partials [kq][col]
  __shared__ float pmr[256];         // mem_read
  __shared__ float pum[4][64];       // U_mem partials
  __shared__ float memf[64];         // mem state f32

  const int t = threadIdx.x;
  const int r = blockIdx.x;
  const int kq = t >> 7;
  const int l7 = t & 127;

  // register-resident gate weight columns j=0..6 (static indices only!)
  uint4 w4[7][8];
  #pragma unroll
  for (int j = 0; j < 7; ++j) {
    const uint4* src = (const uint4*)(Up + ((size_t)(kq * 1024 + l7 + 128 * j)) * 32);
    #pragma unroll
    for (int c4 = 0; c4 < 8; ++c4) w4[j][c4] = src[c4];
  }
  {  // LDS share (j=7)
    const uint4* src = (const uint4*)(Up + ((size_t)(kq * 1024 + l7 + 896)) * 32);
    const int sw = l7 & 7;
    #pragma unroll
    for (int c4 = 0; c4 < 8; ++c4)
      *(uint4*)&Ulds[kq][l7][4 * (c4 ^ sw)] = src[c4];
  }
  {  // W_mem
    int col = t & 255, half = t >> 8, sw = col & 7;
    const uint4* src = (const uint4*)(Wmp + col * 32 + half * 16);
    #pragma unroll
    for (int c4 = 0; c4 < 4; ++c4)
      *(uint4*)&Wml[col][4 * ((half * 4 + c4) ^ sw)] = src[c4];
  }
  {  // U_mem
    int q = t >> 7, m = (t >> 1) & 63, hb = (t & 1) * 4, sw = m & 7;
    const uint4* src = (const uint4*)(Ump + (size_t)t * 16);
    #pragma unroll
    for (int c4 = 0; c4 < 4; ++c4)
      *(uint4*)&Uml[q][m][4 * ((hb + c4) ^ sw)] = src[c4];
  }
  // state init / restore
  float cst = 0.f;
  if (t0 == 0) {
    if (t < 128) hp[t] = 0u;
    if (t < 32) memp[t] = 0u;
    if (t < 64) memf[t] = 0.f;
  } else {
    const u32* s = st + (size_t)r * 512;
    if (t < 128) hp[t] = s[t];
    if (t < 32) memp[t] = s[128 + t];
    if (t < 64) memf[t] = __uint_as_float(s[160 + t]);
    if (t < 256) cst = __uint_as_float(s[224 + t]);
  }

  const int u = t;
  const int swl = l7 & 7;
  const float* Xp = X + (size_t)r * tlen * 1024;
  float* op = out + ((size_t)r * TT + t0) * UU + u;   // valid for t<256 only

  // pre-load x for step 0 (consumed in phase 4; refreshed there for lt+1)
  float xi = 0.f, xf = 0.f, xc = 0.f, xo = 0.f;
  if (t < 256) {
    xi = Xp[u]; xf = Xp[256 + u]; xc = Xp[512 + u]; xo = Xp[768 + u];
  }
  __syncthreads();

  #pragma unroll 1
  for (int lt = 0; lt < tlen; ++lt) {
    // phase 1: gate partial dots over this thread's K-quarter
    float acc[8];
    #pragma unroll
    for (int j = 0; j < 8; ++j) acc[j] = 0.f;
    #pragma unroll
    for (int c4 = 0; c4 < 8; ++c4) {
      uint4 hv = *(const uint4*)&hp[kq * 32 + c4 * 4];  // broadcast
      #pragma unroll
      for (int j = 0; j < 7; ++j) {
        dot2(acc[j], w4[j][c4].x, hv.x); dot2(acc[j], w4[j][c4].y, hv.y);
        dot2(acc[j], w4[j][c4].z, hv.z); dot2(acc[j], w4[j][c4].w, hv.w);
      }
      uint4 wv = *(const uint4*)&Ulds[kq][l7][4 * (c4 ^ swl)];
      dot2(acc[7], wv.x, hv.x); dot2(acc[7], wv.y, hv.y);
      dot2(acc[7], wv.z, hv.z); dot2(acc[7], wv.w, hv.w);
    }
    // phase 2: mem_read[u] = mem_prev @ W_mem (threads 0..255, K=64)
    if (t < 256) {
      float accm = 0.f;
      const int swm = u & 7;
      #pragma unroll
      for (int c4 = 0; c4 < 8; ++c4) {
        uint4 mv = *(const uint4*)&memp[c4 * 4];  // broadcast
        uint4 wv = *(const uint4*)&Wml[u][4 * (c4 ^ swm)];
        dot2(accm, wv.x, mv.x); dot2(accm, wv.y, mv.y);
        dot2(accm, wv.z, mv.z); dot2(accm, wv.w, mv.w);
      }
      pmr[u] = accm;
    }
    #pragma unroll
    for (int j = 0; j < 8; ++j) part[kq][l7 + 128 * j] = acc[j];
    __syncthreads();

    // phase 4: gates, state update, h_new (threads 0..255)
    if (t < 256) {
      float di = part[0][u]       + part[1][u]       + part[2][u]       + part[3][u];
      float df = part[0][256 + u] + part[1][256 + u] + part[2][256 + u] + part[3][256 + u];
      float dc = part[0][512 + u] + part[1][512 + u] + part[2][512 + u] + part[3][512 + u];
      float dz = part[0][768 + u] + part[1][768 + u] + part[2][768 + u] + part[3][768 + u];
      float ig = sigm(xi + di + pmr[u]);
      float fg = sigm(xf + df);
      float ct = tanhf(xc + dc);
      float og = sigm(xo + dz);
      cst = fg * cst + ig * ct;
      float h = og * tanhf(cst);
      *op = h; op += UU;
      ((unsigned short*)hp)[u] = h_bits(h);
      // prefetch x for step lt+1 (covered by phases 7,9 + next phase 1)
      const int ltn = (lt + 1 < tlen) ? lt + 1 : lt;
      const float* Xr = Xp + (size_t)ltn * 1024;
      xi = Xr[u]; xf = Xr[256 + u]; xc = Xr[512 + u]; xo = Xr[768 + u];
    }
    __syncthreads();

    // phase 7: U_mem partials with h_new (threads 0..255)
    if (t < 256) {
      int m = t & 63, q = t >> 6, swq = m & 7;
      float a = 0.f;
      #pragma unroll
      for (int c4 = 0; c4 < 8; ++c4) {
        uint4 hv = *(const uint4*)&hp[q * 32 + c4 * 4];  // broadcast
        uint4 wv = *(const uint4*)&Uml[q][m][4 * (c4 ^ swq)];
        dot2(a, wv.x, hv.x); dot2(a, wv.y, hv.y);
        dot2(a, wv.z, hv.z); dot2(a, wv.w, hv.w);
      }
      pum[q][m] = a;
    }
    __syncthreads();

    // phase 9: mem state update (threads 0..63)
    if (t < 64) {
      float nm = memf[t] + 0.1f * (pum[0][t] + pum[1][t] + pum[2][t] + pum[3][t]);
      memf[t] = nm;
      ((unsigned short*)memp)[t] = h_bits(nm);
    }
    __syncthreads();
  }
  // save state for next chunk
  {
    u32* s = st + (size_t)r * 512;
    if (t < 128) s[t] = hp[t];
    if (t < 32) s[128 + t] = memp[t];
    if (t < 64) s[160 + t] = __float_as_uint(memf[t]);
    if (t < 256) s[224 + t] = __float_as_uint(cst);
  }
}

// ---------- launch ----------
extern "C" void kernel_launch(void* const* d_in, const int* in_sizes, int n_in,
                              void* d_out, int out_size, void* d_ws, size_t ws_size,
                              hipStream_t stream) {
  const float* inp  = (const float*)d_in[0];
  const float* Wi   = (const float*)d_in[1];
  const float* Wf   = (const float*)d_in[2];
  const float* Wc   = (const float*)d_in[3];
  const float* Wo   = (const float*)d_in[4];
  const float* Ui   = (const float*)d_in[5];
  const float* Uf   = (const float*)d_in[6];
  const float* Uc   = (const float*)d_in[7];
  const float* Uo   = (const float*)d_in[8];
  const float* Wmem = (const float*)d_in[9];
  const float* Umem = (const float*)d_in[10];
  const float* bi   = (const float*)d_in[11];
  const float* bfv  = (const float*)d_in[12];
  const float* bc   = (const float*)d_in[13];
  const float* bo   = (const float*)d_in[14];

  char* ws = (char*)d_ws;
  u32* Up     = (u32*)(ws);                 // 512 KB
  u32* Wcx    = (u32*)(ws + 524288);        // 256 KB
  u32* Wmp    = (u32*)(ws + 786432);        //  32 KB
  u32* Ump    = (u32*)(ws + 819200);        //  32 KB
  float* bias = (float*)(ws + 851968);      //   4 KB
  u32* st     = (u32*)(ws + (1 << 20));     // 256 KB state
  float* X    = (float*)(ws + (2u << 20));  // B*tlen*1024 f32

  // largest T-chunk whose X buffer fits in ws
  int tlen = 1024;
  while (tlen > 64 && (size_t)(2u << 20) + (size_t)BB * tlen * 4096 > ws_size) tlen >>= 1;
  const int nch = TT / tlen;

  pack_kernel<<<256, 256, 0, stream>>>(Wi, Wf, Wc, Wo, Ui, Uf, Uc, Uo, Wmem, Umem,
                                       bi, bfv, bc, bo, Up, Wcx, Wmp, Ump, bias);
  for (int ch = 0; ch < nch; ++ch) {
    int t0 = ch * tlen;
    xproj_kernel<<<2 * tlen, 512, 0, stream>>>(inp, Wcx, bias, X, t0, tlen);
    rec_kernel<<<BB, 512, 0, stream>>>(Up, Wmp, Ump, X, (float*)d_out, st, t0, tlen);
  }
}

// Round 5
// 5309.866 us; speedup vs baseline: 1.4458x; 1.4458x over previous
//
#include <hip/hip_runtime.h>
#include <cstdint>
#include <cstddef>

using u32 = unsigned int;
typedef _Float16 f16;
typedef _Float16 f16x2 __attribute__((ext_vector_type(2)));

// ---------- helpers ----------
__device__ __forceinline__ u32 pack2h(float a, float b) {
  f16x2 p; p.x = (f16)a; p.y = (f16)b;
  return __builtin_bit_cast(u32, p);
}
__device__ __forceinline__ unsigned short h_bits(float x) {
  f16 h = (f16)x; return __builtin_bit_cast(unsigned short, h);
}
// acc += dot2(f16x2 a, f16x2 b)  -- v_dot2_f32_f16
__device__ __forceinline__ void dot2(float& acc, u32 a, u32 b) {
#if __has_builtin(__builtin_amdgcn_fdot2)
  acc = __builtin_amdgcn_fdot2(__builtin_bit_cast(f16x2, a),
                               __builtin_bit_cast(f16x2, b), acc, false);
#else
  f16x2 x = __builtin_bit_cast(f16x2, a), y = __builtin_bit_cast(f16x2, b);
  acc = fmaf((float)x.y, (float)y.y, fmaf((float)x.x, (float)y.x, acc));
#endif
}
#define DOT4(A, W, H) do { dot2(A, (W).x, (H).x); dot2(A, (W).y, (H).y); \
                           dot2(A, (W).z, (H).z); dot2(A, (W).w, (H).w); } while (0)

__device__ __forceinline__ float sigm(float x) {
  return __builtin_amdgcn_rcpf(1.f + __expf(-x));
}
__device__ __forceinline__ float tanh_fast(float x) {
  float xc = fminf(fmaxf(x, -12.f), 12.f);
  float e = __expf(2.f * xc);
  return (e - 1.f) * __builtin_amdgcn_rcpf(e + 1.f);
}

// ---------- sizes ----------
#define BB 128
#define TT 1024
#define DD 128
#define UU 256
#define MM 64
#define N_UPC 131072  // U gates packed [col][kd0..127], col = g*256+u
#define N_WCX 65536   // W_cat packed [col][kd0..63]
#define N_WMT 8192    // W_mem packed transposed: uint4 chunk (k8, u), k8=0..7
#define N_UMT 8192    // U_mem packed transposed: uint4 chunk (c, m), c=0..31
#define N_BIAS 1024   // f32 bias

// ---------- pack: f32 weights -> f16-pair layouts ----------
__global__ void pack_kernel(const float* Wi, const float* Wf, const float* Wc, const float* Wo,
                            const float* Ui, const float* Uf, const float* Uc, const float* Uo,
                            const float* Wmem, const float* Umem,
                            const float* bi, const float* bfv, const float* bc, const float* bo,
                            u32* Upc, u32* Wcx, u32* WmT, u32* UmT, float* bias) {
  int idx = blockIdx.x * blockDim.x + threadIdx.x;
  const int total = N_UPC + N_WCX + N_WMT + N_UMT + N_BIAS;
  for (int i = idx; i < total; i += gridDim.x * blockDim.x) {
    if (i < N_UPC) {
      int col = i >> 7, kd = i & 127, g = col >> 8, u = col & 255, k0 = kd * 2;
      const float* Ug = (g == 0 ? Ui : g == 1 ? Uf : g == 2 ? Uc : Uo);
      Upc[i] = pack2h(Ug[k0 * 256 + u], Ug[(k0 + 1) * 256 + u]);
    } else if (i < N_UPC + N_WCX) {
      int j = i - N_UPC;
      int col = j >> 6, kd = j & 63, g = col >> 8, u = col & 255, k0 = kd * 2;
      const float* Wg = (g == 0 ? Wi : g == 1 ? Wf : g == 2 ? Wc : Wo);
      Wcx[j] = pack2h(Wg[k0 * 256 + u], Wg[(k0 + 1) * 256 + u]);
    } else if (i < N_UPC + N_WCX + N_WMT) {
      int j = i - (N_UPC + N_WCX);
      int d = j & 3, u = (j >> 2) & 255, k8 = j >> 10, m0 = k8 * 8 + d * 2;
      WmT[j] = pack2h(Wmem[m0 * 256 + u], Wmem[(m0 + 1) * 256 + u]);
    } else if (i < N_UPC + N_WCX + N_WMT + N_UMT) {
      int j = i - (N_UPC + N_WCX + N_WMT);
      int d = j & 3, m = (j >> 2) & 63, c = j >> 8, k = c * 8 + d * 2;
      UmT[j] = pack2h(Umem[k * 64 + m], Umem[(k + 1) * 64 + m]);
    } else {
      int j = i - (N_UPC + N_WCX + N_WMT + N_UMT);
      int g = j >> 8;
      const float* bg = (g == 0 ? bi : g == 1 ? bfv : g == 2 ? bc : bo);
      bias[j] = bg[j & 255];
    }
  }
}

// ---------- x projection: X[ci][1024] = inp_row @ W_cat + bias (f32 out) ----------
__global__ __launch_bounds__(512) void xproj_kernel(const float* __restrict__ inp,
                                                    const u32* __restrict__ Wcx,
                                                    const float* __restrict__ bias,
                                                    float* __restrict__ X,
                                                    int t0, int tlen) {
  __shared__ u32 ilds[64][64];  // 64 rows x 64 f16-pair dwords
  const int t = threadIdx.x;
  const int blk = blockIdx.x;
  const int bpr = tlen >> 6;
  const int r = blk / bpr;
  const int boff = blk - r * bpr;
  const int ts0 = t0 + boff * 64;
  const float* ip = inp + ((size_t)r * TT + ts0) * DD;
  #pragma unroll
  for (int i = 0; i < 4; ++i) {
    int fi = t + i * 512;
    float4 v = ((const float4*)ip)[fi];
    int row = fi >> 5, kd = (fi & 31) * 2;
    ilds[row][kd]     = pack2h(v.x, v.y);
    ilds[row][kd + 1] = pack2h(v.z, v.w);
  }
  __syncthreads();
  const int c0 = 2 * t, c1 = 2 * t + 1;
  uint4 wa4[16], wb4[16];
  const uint4* Wa = (const uint4*)(Wcx + (size_t)c0 * 64);
  const uint4* Wb = (const uint4*)(Wcx + (size_t)c1 * 64);
  #pragma unroll
  for (int i = 0; i < 16; ++i) { wa4[i] = Wa[i]; wb4[i] = Wb[i]; }
  const float ba = bias[c0], bb = bias[c1];
  const size_t cibase = (size_t)r * tlen + (size_t)boff * 64;
  for (int rl = 0; rl < 64; ++rl) {
    float a = ba, b = bb;
    #pragma unroll
    for (int c4 = 0; c4 < 16; ++c4) {
      uint4 hv = *(const uint4*)&ilds[rl][c4 * 4];
      DOT4(a, wa4[c4], hv);
      DOT4(b, wb4[c4], hv);
    }
    float2 st2; st2.x = a; st2.y = b;
    *(float2*)&X[(cibase + rl) * 1024 + c0] = st2;
  }
}

// ---------- recurrent kernel: 128 blocks x 256 threads (1 wave/SIMD -> 512 VGPR) ----
// Thread u owns unit u: gates i,f,c weights in 384 REG dwords; gate o in 128KB LDS
// transposed tile gT[c4][u] (lane-consecutive 16B reads); W_mem/U_mem streamed from L2.
__global__ __launch_bounds__(256, 1) void rec_kernel(const u32* __restrict__ Upc,
                                                     const u32* __restrict__ WmT,
                                                     const u32* __restrict__ UmT,
                                                     const float* __restrict__ X,
                                                     float* __restrict__ out,
                                                     u32* __restrict__ st,
                                                     int t0, int tlen) {
  __shared__ uint4 gT[32 * 256];            // 128KB gate-o, chunk (c4, u)
  __shared__ alignas(16) u32 hpD[2][128];   // h as f16 pairs, double-buffered
  __shared__ alignas(16) u32 memp[32];      // mem as f16 pairs
  __shared__ float pum[4][64];              // U_mem partials
  __shared__ float memf[64];                // mem state f32

  const int t = threadIdx.x;   // 0..255
  const int r = blockIdx.x;
  const int u = t;

  // register-resident gate columns i,f,c (static indices only)
  uint4 w4[3][32];
  #pragma unroll
  for (int g = 0; g < 3; ++g) {
    const uint4* src = (const uint4*)(Upc + ((size_t)(g * 256 + u)) * 128);
    #pragma unroll
    for (int c4 = 0; c4 < 32; ++c4) w4[g][c4] = src[c4];
  }
  {  // stage gate-o into transposed LDS tile
    const uint4* src = (const uint4*)(Upc + ((size_t)(768 + u)) * 128);
    #pragma unroll
    for (int c4 = 0; c4 < 32; ++c4) gT[c4 * 256 + u] = src[c4];
  }
  // state init / restore
  float cst = 0.f;
  if (t0 == 0) {
    if (t < 128) hpD[0][t] = 0u;
    if (t < 32) memp[t] = 0u;
    if (t < 64) memf[t] = 0.f;
  } else {
    const u32* s = st + (size_t)r * 512;
    if (t < 128) hpD[0][t] = s[t];
    if (t < 32) memp[t] = s[128 + t];
    if (t < 64) memf[t] = __uint_as_float(s[160 + t]);
    cst = __uint_as_float(s[224 + t]);
  }
  __syncthreads();

  const float* Xp = X + (size_t)r * tlen * 1024;
  float* op = out + ((size_t)r * TT + t0) * UU + u;
  const int qm = t >> 6, mm = t & 63;   // phase-B mapping

  #pragma unroll 1
  for (int lt = 0; lt < tlen; ++lt) {
    const int p = lt & 1;
    // defeat LICM on the per-step L2 weight streams (would blow VGPR budget)
    u32 zoff = 0;
    asm volatile("" : "+v"(zoff));
    const uint4* WmTv = (const uint4*)WmT + zoff;
    const uint4* UmTv = (const uint4*)UmT + zoff;

    // x for this step (consumed ~1000 cyc later at the gates)
    const float* Xr = Xp + (size_t)lt * 1024;
    float xi = Xr[u], xf = Xr[256 + u], xc = Xr[512 + u], xo = Xr[768 + u];

    // W_mem stream, first half
    uint4 wma0 = WmTv[0 * 256 + u], wma1 = WmTv[1 * 256 + u];
    uint4 wma2 = WmTv[2 * 256 + u], wma3 = WmTv[3 * 256 + u];

    float a[4][2];
    #pragma unroll
    for (int g = 0; g < 4; ++g) { a[g][0] = 0.f; a[g][1] = 0.f; }
    float am0 = 0.f, am1 = 0.f;

    #pragma unroll
    for (int c4 = 0; c4 < 16; ++c4) {
      uint4 hv = *(const uint4*)&hpD[p][c4 * 4];   // broadcast
      uint4 ov = gT[c4 * 256 + u];
      DOT4(a[0][c4 & 1], w4[0][c4], hv);
      DOT4(a[1][c4 & 1], w4[1][c4], hv);
      DOT4(a[2][c4 & 1], w4[2][c4], hv);
      DOT4(a[3][c4 & 1], ov, hv);
    }
    {  // mem_read first half + issue second half
      uint4 m0 = *(const uint4*)&memp[0],  m1 = *(const uint4*)&memp[4];
      uint4 m2 = *(const uint4*)&memp[8],  m3 = *(const uint4*)&memp[12];
      DOT4(am0, wma0, m0); DOT4(am1, wma1, m1);
      DOT4(am0, wma2, m2); DOT4(am1, wma3, m3);
    }
    uint4 wmb0 = WmTv[4 * 256 + u], wmb1 = WmTv[5 * 256 + u];
    uint4 wmb2 = WmTv[6 * 256 + u], wmb3 = WmTv[7 * 256 + u];
    #pragma unroll
    for (int c4 = 16; c4 < 32; ++c4) {
      uint4 hv = *(const uint4*)&hpD[p][c4 * 4];
      uint4 ov = gT[c4 * 256 + u];
      DOT4(a[0][c4 & 1], w4[0][c4], hv);
      DOT4(a[1][c4 & 1], w4[1][c4], hv);
      DOT4(a[2][c4 & 1], w4[2][c4], hv);
      DOT4(a[3][c4 & 1], ov, hv);
    }
    {  // mem_read second half
      uint4 m4 = *(const uint4*)&memp[16], m5 = *(const uint4*)&memp[20];
      uint4 m6 = *(const uint4*)&memp[24], m7 = *(const uint4*)&memp[28];
      DOT4(am0, wmb0, m4); DOT4(am1, wmb1, m5);
      DOT4(am0, wmb2, m6); DOT4(am1, wmb3, m7);
    }
    // issue U_mem stream for phase B (latency covered by gates + barrier)
    uint4 um[8];
    #pragma unroll
    for (int kk = 0; kk < 8; ++kk) um[kk] = UmTv[(qm * 8 + kk) * 64 + mm];

    // gates + state update (all thread-local)
    float di = a[0][0] + a[0][1], df = a[1][0] + a[1][1];
    float dc = a[2][0] + a[2][1], dz = a[3][0] + a[3][1];
    float ig = sigm(xi + di + (am0 + am1));
    float fg = sigm(xf + df);
    float ctl = tanh_fast(xc + dc);
    float og = sigm(xo + dz);
    cst = fg * cst + ig * ctl;
    float h = og * tanh_fast(cst);
    *op = h; op += UU;
    ((unsigned short*)&hpD[p ^ 1][0])[u] = h_bits(h);
    __syncthreads();

    // phase B: U_mem partials with h_new
    {
      float b0 = 0.f, b1 = 0.f;
      #pragma unroll
      for (int kk = 0; kk < 8; ++kk) {
        uint4 hv = *(const uint4*)&hpD[p ^ 1][(qm * 8 + kk) * 4];  // broadcast
        if (kk & 1) { DOT4(b1, um[kk], hv); } else { DOT4(b0, um[kk], hv); }
      }
      pum[qm][mm] = b0 + b1;
    }
    __syncthreads();

    // phase C: mem state update
    if (t < 64) {
      float nm = memf[t] + 0.1f * ((pum[0][t] + pum[1][t]) + (pum[2][t] + pum[3][t]));
      memf[t] = nm;
      ((unsigned short*)memp)[t] = h_bits(nm);
    }
    __syncthreads();
  }
  // save state for next chunk
  {
    u32* s = st + (size_t)r * 512;
    const int pf = tlen & 1;
    if (t < 128) s[t] = hpD[pf][t];
    if (t < 32) s[128 + t] = memp[t];
    if (t < 64) s[160 + t] = __float_as_uint(memf[t]);
    s[224 + t] = __float_as_uint(cst);
  }
}

// ---------- launch ----------
extern "C" void kernel_launch(void* const* d_in, const int* in_sizes, int n_in,
                              void* d_out, int out_size, void* d_ws, size_t ws_size,
                              hipStream_t stream) {
  const float* inp  = (const float*)d_in[0];
  const float* Wi   = (const float*)d_in[1];
  const float* Wf   = (const float*)d_in[2];
  const float* Wc   = (const float*)d_in[3];
  const float* Wo   = (const float*)d_in[4];
  const float* Ui   = (const float*)d_in[5];
  const float* Uf   = (const float*)d_in[6];
  const float* Uc   = (const float*)d_in[7];
  const float* Uo   = (const float*)d_in[8];
  const float* Wmem = (const float*)d_in[9];
  const float* Umem = (const float*)d_in[10];
  const float* bi   = (const float*)d_in[11];
  const float* bfv  = (const float*)d_in[12];
  const float* bc   = (const float*)d_in[13];
  const float* bo   = (const float*)d_in[14];

  char* ws = (char*)d_ws;
  u32* Upc    = (u32*)(ws);                 // 512 KB
  u32* Wcx    = (u32*)(ws + 524288);        // 256 KB
  u32* WmT    = (u32*)(ws + 786432);        //  32 KB
  u32* UmT    = (u32*)(ws + 819200);        //  32 KB
  float* bias = (float*)(ws + 851968);      //   4 KB
  u32* st     = (u32*)(ws + (1 << 20));     // 256 KB state
  float* X    = (float*)(ws + (2u << 20));  // B*tlen*1024 f32

  int tlen = 1024;
  while (tlen > 64 && (size_t)(2u << 20) + (size_t)BB * tlen * 4096 > ws_size) tlen >>= 1;
  const int nch = TT / tlen;

  pack_kernel<<<256, 256, 0, stream>>>(Wi, Wf, Wc, Wo, Ui, Uf, Uc, Uo, Wmem, Umem,
                                       bi, bfv, bc, bo, Upc, Wcx, WmT, UmT, bias);
  for (int ch = 0; ch < nch; ++ch) {
    int t0 = ch * tlen;
    xproj_kernel<<<2 * tlen, 512, 0, stream>>>(inp, Wcx, bias, X, t0, tlen);
    rec_kernel<<<BB, 256, 0, stream>>>(Upc, WmT, UmT, X, (float*)d_out, st, t0, tlen);
  }
}

// Round 6
// 4984.924 us; speedup vs baseline: 1.5400x; 1.0652x over previous
//
#include <hip/hip_runtime.h>
#include <cstdint>
#include <cstddef>

using u32 = unsigned int;
typedef _Float16 f16;
typedef _Float16 f16x2 __attribute__((ext_vector_type(2)));

// ---------- helpers ----------
__device__ __forceinline__ u32 pack2h(float a, float b) {
  f16x2 p; p.x = (f16)a; p.y = (f16)b;
  return __builtin_bit_cast(u32, p);
}
__device__ __forceinline__ unsigned short h_bits(float x) {
  f16 h = (f16)x; return __builtin_bit_cast(unsigned short, h);
}
// acc += dot2(f16x2 a, f16x2 b)  -- v_dot2_f32_f16
__device__ __forceinline__ void dot2(float& acc, u32 a, u32 b) {
#if __has_builtin(__builtin_amdgcn_fdot2)
  acc = __builtin_amdgcn_fdot2(__builtin_bit_cast(f16x2, a),
                               __builtin_bit_cast(f16x2, b), acc, false);
#else
  f16x2 x = __builtin_bit_cast(f16x2, a), y = __builtin_bit_cast(f16x2, b);
  acc = fmaf((float)x.y, (float)y.y, fmaf((float)x.x, (float)y.x, acc));
#endif
}
#define DOT4(A, W, H) do { dot2(A, (W).x, (H).x); dot2(A, (W).y, (H).y); \
                           dot2(A, (W).z, (H).z); dot2(A, (W).w, (H).w); } while (0)

__device__ __forceinline__ float sigm(float x) {
  return __builtin_amdgcn_rcpf(1.f + __expf(-x));
}
__device__ __forceinline__ float tanh_fast(float x) {
  float xc = fminf(fmaxf(x, -12.f), 12.f);
  float e = __expf(2.f * xc);
  return (e - 1.f) * __builtin_amdgcn_rcpf(e + 1.f);
}

// ---------- sizes ----------
#define BB 128
#define TT 1024
#define DD 128
#define UU 256
#define MM 64
#define N_UPC 131072  // U gates packed [col][kd0..127], col = g*256+u
#define N_WCX 65536   // W_cat packed [col][kd0..63]
#define N_WMT 8192    // W_mem packed transposed: uint4 chunk (k8, u), k8=0..7
#define N_UMT 8192    // U_mem packed transposed: uint4 chunk (c, m), c=0..31
#define N_BIAS 1024   // f32 bias

// ---------- pack: f32 weights -> f16-pair layouts ----------
__global__ void pack_kernel(const float* Wi, const float* Wf, const float* Wc, const float* Wo,
                            const float* Ui, const float* Uf, const float* Uc, const float* Uo,
                            const float* Wmem, const float* Umem,
                            const float* bi, const float* bfv, const float* bc, const float* bo,
                            u32* Upc, u32* Wcx, u32* WmT, u32* UmT, float* bias) {
  int idx = blockIdx.x * blockDim.x + threadIdx.x;
  const int total = N_UPC + N_WCX + N_WMT + N_UMT + N_BIAS;
  for (int i = idx; i < total; i += gridDim.x * blockDim.x) {
    if (i < N_UPC) {
      int col = i >> 7, kd = i & 127, g = col >> 8, u = col & 255, k0 = kd * 2;
      const float* Ug = (g == 0 ? Ui : g == 1 ? Uf : g == 2 ? Uc : Uo);
      Upc[i] = pack2h(Ug[k0 * 256 + u], Ug[(k0 + 1) * 256 + u]);
    } else if (i < N_UPC + N_WCX) {
      int j = i - N_UPC;
      int col = j >> 6, kd = j & 63, g = col >> 8, u = col & 255, k0 = kd * 2;
      const float* Wg = (g == 0 ? Wi : g == 1 ? Wf : g == 2 ? Wc : Wo);
      Wcx[j] = pack2h(Wg[k0 * 256 + u], Wg[(k0 + 1) * 256 + u]);
    } else if (i < N_UPC + N_WCX + N_WMT) {
      int j = i - (N_UPC + N_WCX);
      int d = j & 3, u = (j >> 2) & 255, k8 = j >> 10, m0 = k8 * 8 + d * 2;
      WmT[j] = pack2h(Wmem[m0 * 256 + u], Wmem[(m0 + 1) * 256 + u]);
    } else if (i < N_UPC + N_WCX + N_WMT + N_UMT) {
      int j = i - (N_UPC + N_WCX + N_WMT);
      int d = j & 3, m = (j >> 2) & 63, c = j >> 8, k = c * 8 + d * 2;
      UmT[j] = pack2h(Umem[k * 64 + m], Umem[(k + 1) * 64 + m]);
    } else {
      int j = i - (N_UPC + N_WCX + N_WMT + N_UMT);
      int g = j >> 8;
      const float* bg = (g == 0 ? bi : g == 1 ? bfv : g == 2 ? bc : bo);
      bias[j] = bg[j & 255];
    }
  }
}

// ---------- x projection: X[ci][1024] = inp_row @ W_cat + bias (f32 out) ----------
__global__ __launch_bounds__(512) void xproj_kernel(const float* __restrict__ inp,
                                                    const u32* __restrict__ Wcx,
                                                    const float* __restrict__ bias,
                                                    float* __restrict__ X,
                                                    int t0, int tlen) {
  __shared__ u32 ilds[64][64];  // 64 rows x 64 f16-pair dwords
  const int t = threadIdx.x;
  const int blk = blockIdx.x;
  const int bpr = tlen >> 6;
  const int r = blk / bpr;
  const int boff = blk - r * bpr;
  const int ts0 = t0 + boff * 64;
  const float* ip = inp + ((size_t)r * TT + ts0) * DD;
  #pragma unroll
  for (int i = 0; i < 4; ++i) {
    int fi = t + i * 512;
    float4 v = ((const float4*)ip)[fi];
    int row = fi >> 5, kd = (fi & 31) * 2;
    ilds[row][kd]     = pack2h(v.x, v.y);
    ilds[row][kd + 1] = pack2h(v.z, v.w);
  }
  __syncthreads();
  const int c0 = 2 * t, c1 = 2 * t + 1;
  uint4 wa4[16], wb4[16];
  const uint4* Wa = (const uint4*)(Wcx + (size_t)c0 * 64);
  const uint4* Wb = (const uint4*)(Wcx + (size_t)c1 * 64);
  #pragma unroll
  for (int i = 0; i < 16; ++i) { wa4[i] = Wa[i]; wb4[i] = Wb[i]; }
  const float ba = bias[c0], bb = bias[c1];
  const size_t cibase = (size_t)r * tlen + (size_t)boff * 64;
  for (int rl = 0; rl < 64; ++rl) {
    float a = ba, b = bb;
    #pragma unroll
    for (int c4 = 0; c4 < 16; ++c4) {
      uint4 hv = *(const uint4*)&ilds[rl][c4 * 4];
      DOT4(a, wa4[c4], hv);
      DOT4(b, wb4[c4], hv);
    }
    float2 st2; st2.x = a; st2.y = b;
    *(float2*)&X[(cibase + rl) * 1024 + c0] = st2;
  }
}

// ---------- recurrent kernel: 128 blocks x 256 threads (1 wave/SIMD -> 512 reg budget)
// Thread u owns unit u: gates i,f,c weights in 384 reg dwords (AGPR-backed); gate o in
// 128KB LDS tile gT[c4][u]; W_mem/U_mem streamed from L2; 2-deep SW pipeline on LDS reads.
__global__ __launch_bounds__(256, 1) void rec_kernel(const u32* __restrict__ Upc,
                                                     const u32* __restrict__ WmT,
                                                     const u32* __restrict__ UmT,
                                                     const float* __restrict__ X,
                                                     float* __restrict__ out,
                                                     u32* __restrict__ st,
                                                     int t0, int tlen) {
  __shared__ uint4 gT[32 * 256];            // 128KB gate-o, chunk (c4, u)
  __shared__ alignas(16) u32 hpD[2][128];   // h as f16 pairs, double-buffered
  __shared__ alignas(16) u32 memp[32];      // mem as f16 pairs
  __shared__ float pum[4][64];              // U_mem partials
  __shared__ float memf[64];                // mem state f32

  const int t = threadIdx.x;   // 0..255
  const int r = blockIdx.x;
  const int u = t;

  // register-resident gate columns i,f,c (static indices only)
  uint4 w4[3][32];
  #pragma unroll
  for (int g = 0; g < 3; ++g) {
    const uint4* src = (const uint4*)(Upc + ((size_t)(g * 256 + u)) * 128);
    #pragma unroll
    for (int c4 = 0; c4 < 32; ++c4) w4[g][c4] = src[c4];
  }
  {  // stage gate-o into transposed LDS tile
    const uint4* src = (const uint4*)(Upc + ((size_t)(768 + u)) * 128);
    #pragma unroll
    for (int c4 = 0; c4 < 32; ++c4) gT[c4 * 256 + u] = src[c4];
  }
  // state init / restore
  float cst = 0.f;
  if (t0 == 0) {
    if (t < 128) hpD[0][t] = 0u;
    if (t < 32) memp[t] = 0u;
    if (t < 64) memf[t] = 0.f;
  } else {
    const u32* s = st + (size_t)r * 512;
    if (t < 128) hpD[0][t] = s[t];
    if (t < 32) memp[t] = s[128 + t];
    if (t < 64) memf[t] = __uint_as_float(s[160 + t]);
    cst = __uint_as_float(s[224 + t]);
  }
  __syncthreads();

  const float* Xp = X + (size_t)r * tlen * 1024;
  float* op = out + ((size_t)r * TT + t0) * UU + u;
  const int qm = t >> 6, mm = t & 63;   // phase-B mapping

  // x for step 0 (subsequent steps prefetched at the h-store point)
  float xi = Xp[u], xf = Xp[256 + u], xc = Xp[512 + u], xo = Xp[768 + u];

  #pragma unroll 1
  for (int lt = 0; lt < tlen; ++lt) {
    const int p = lt & 1;
    // defeat LICM on the per-step L2 weight streams (would blow reg budget)
    u32 zoff = 0;
    asm volatile("" : "+v"(zoff));
    const uint4* WmTv = (const uint4*)WmT + zoff;
    const uint4* UmTv = (const uint4*)UmT + zoff;

    // W_mem stream, first half; U_mem stream, first half
    uint4 wma0 = WmTv[0 * 256 + u], wma1 = WmTv[1 * 256 + u];
    uint4 wma2 = WmTv[2 * 256 + u], wma3 = WmTv[3 * 256 + u];
    uint4 um0 = UmTv[(qm * 8 + 0) * 64 + mm], um1 = UmTv[(qm * 8 + 1) * 64 + mm];
    uint4 um2 = UmTv[(qm * 8 + 2) * 64 + mm], um3 = UmTv[(qm * 8 + 3) * 64 + mm];

    float a[4][2];
    #pragma unroll
    for (int g = 0; g < 4; ++g) { a[g][0] = 0.f; a[g][1] = 0.f; }
    float am0 = 0.f, am1 = 0.f;

    // ---- gate dots, 2-deep software-pipelined LDS reads ----
    uint4 hvA = *(const uint4*)&hpD[p][0];
    uint4 ovA = gT[0 * 256 + u];
    uint4 hvB = *(const uint4*)&hpD[p][4];
    uint4 ovB = gT[1 * 256 + u];
    #pragma unroll
    for (int c4 = 0; c4 < 16; c4 += 2) {
      uint4 hv = hvA, ov = ovA;
      hvA = *(const uint4*)&hpD[p][(c4 + 2) * 4];
      ovA = gT[(c4 + 2) * 256 + u];
      DOT4(a[0][0], w4[0][c4], hv);
      DOT4(a[1][0], w4[1][c4], hv);
      DOT4(a[2][0], w4[2][c4], hv);
      DOT4(a[3][0], ov, hv);
      uint4 hv2 = hvB, ov2 = ovB;
      hvB = *(const uint4*)&hpD[p][(c4 + 3) * 4];
      ovB = gT[(c4 + 3) * 256 + u];
      DOT4(a[0][1], w4[0][c4 + 1], hv2);
      DOT4(a[1][1], w4[1][c4 + 1], hv2);
      DOT4(a[2][1], w4[2][c4 + 1], hv2);
      DOT4(a[3][1], ov2, hv2);
    }
    {  // mem_read first half (memp broadcasts; short dots, covered by pipeline)
      uint4 m0 = *(const uint4*)&memp[0],  m1 = *(const uint4*)&memp[4];
      uint4 m2 = *(const uint4*)&memp[8],  m3 = *(const uint4*)&memp[12];
      DOT4(am0, wma0, m0); DOT4(am1, wma1, m1);
      DOT4(am0, wma2, m2); DOT4(am1, wma3, m3);
    }
    uint4 wmb0 = WmTv[4 * 256 + u], wmb1 = WmTv[5 * 256 + u];
    uint4 wmb2 = WmTv[6 * 256 + u], wmb3 = WmTv[7 * 256 + u];
    #pragma unroll
    for (int c4 = 16; c4 < 32; c4 += 2) {
      uint4 hv = hvA, ov = ovA;
      if (c4 + 2 < 32) { hvA = *(const uint4*)&hpD[p][(c4 + 2) * 4]; ovA = gT[(c4 + 2) * 256 + u]; }
      DOT4(a[0][0], w4[0][c4], hv);
      DOT4(a[1][0], w4[1][c4], hv);
      DOT4(a[2][0], w4[2][c4], hv);
      DOT4(a[3][0], ov, hv);
      uint4 hv2 = hvB, ov2 = ovB;
      if (c4 + 3 < 32) { hvB = *(const uint4*)&hpD[p][(c4 + 3) * 4]; ovB = gT[(c4 + 3) * 256 + u]; }
      DOT4(a[0][1], w4[0][c4 + 1], hv2);
      DOT4(a[1][1], w4[1][c4 + 1], hv2);
      DOT4(a[2][1], w4[2][c4 + 1], hv2);
      DOT4(a[3][1], ov2, hv2);
    }
    {  // mem_read second half
      uint4 m4 = *(const uint4*)&memp[16], m5 = *(const uint4*)&memp[20];
      uint4 m6 = *(const uint4*)&memp[24], m7 = *(const uint4*)&memp[28];
      DOT4(am0, wmb0, m4); DOT4(am1, wmb1, m5);
      DOT4(am0, wmb2, m6); DOT4(am1, wmb3, m7);
    }
    // U_mem stream, second half (consumed in phase B after the barrier)
    uint4 um4 = UmTv[(qm * 8 + 4) * 64 + mm], um5 = UmTv[(qm * 8 + 5) * 64 + mm];
    uint4 um6 = UmTv[(qm * 8 + 6) * 64 + mm], um7 = UmTv[(qm * 8 + 7) * 64 + mm];

    // gates + state update (all thread-local)
    float di = a[0][0] + a[0][1], df = a[1][0] + a[1][1];
    float dc = a[2][0] + a[2][1], dz = a[3][0] + a[3][1];
    float ig = sigm(xi + di + (am0 + am1));
    float fg = sigm(xf + df);
    float ctl = tanh_fast(xc + dc);
    float og = sigm(xo + dz);
    cst = fg * cst + ig * ctl;
    float h = og * tanh_fast(cst);
    *op = h; op += UU;
    ((unsigned short*)&hpD[p ^ 1][0])[u] = h_bits(h);
    // prefetch x for step lt+1 (full-step latency cover)
    {
      const int ltn = (lt + 1 < tlen) ? lt + 1 : lt;
      const float* Xr = Xp + (size_t)ltn * 1024;
      xi = Xr[u]; xf = Xr[256 + u]; xc = Xr[512 + u]; xo = Xr[768 + u];
    }
    __syncthreads();

    // phase B: U_mem partials with h_new (2-deep pipelined broadcasts)
    {
      float b0 = 0.f, b1 = 0.f;
      uint4 pvA = *(const uint4*)&hpD[p ^ 1][(qm * 8 + 0) * 4];
      uint4 pvB = *(const uint4*)&hpD[p ^ 1][(qm * 8 + 1) * 4];
      uint4 pv;
      pv = pvA; pvA = *(const uint4*)&hpD[p ^ 1][(qm * 8 + 2) * 4]; DOT4(b0, um0, pv);
      pv = pvB; pvB = *(const uint4*)&hpD[p ^ 1][(qm * 8 + 3) * 4]; DOT4(b1, um1, pv);
      pv = pvA; pvA = *(const uint4*)&hpD[p ^ 1][(qm * 8 + 4) * 4]; DOT4(b0, um2, pv);
      pv = pvB; pvB = *(const uint4*)&hpD[p ^ 1][(qm * 8 + 5) * 4]; DOT4(b1, um3, pv);
      pv = pvA; pvA = *(const uint4*)&hpD[p ^ 1][(qm * 8 + 6) * 4]; DOT4(b0, um4, pv);
      pv = pvB; pvB = *(const uint4*)&hpD[p ^ 1][(qm * 8 + 7) * 4]; DOT4(b1, um5, pv);
      pv = pvA; DOT4(b0, um6, pv);
      pv = pvB; DOT4(b1, um7, pv);
      pum[qm][mm] = b0 + b1;
    }
    __syncthreads();

    // phase C: mem state update
    if (t < 64) {
      float nm = memf[t] + 0.1f * ((pum[0][t] + pum[1][t]) + (pum[2][t] + pum[3][t]));
      memf[t] = nm;
      ((unsigned short*)memp)[t] = h_bits(nm);
    }
    __syncthreads();
  }
  // save state for next chunk
  {
    u32* s = st + (size_t)r * 512;
    const int pf = tlen & 1;
    if (t < 128) s[t] = hpD[pf][t];
    if (t < 32) s[128 + t] = memp[t];
    if (t < 64) s[160 + t] = __float_as_uint(memf[t]);
    s[224 + t] = __float_as_uint(cst);
  }
}

// ---------- launch ----------
extern "C" void kernel_launch(void* const* d_in, const int* in_sizes, int n_in,
                              void* d_out, int out_size, void* d_ws, size_t ws_size,
                              hipStream_t stream) {
  const float* inp  = (const float*)d_in[0];
  const float* Wi   = (const float*)d_in[1];
  const float* Wf   = (const float*)d_in[2];
  const float* Wc   = (const float*)d_in[3];
  const float* Wo   = (const float*)d_in[4];
  const float* Ui   = (const float*)d_in[5];
  const float* Uf   = (const float*)d_in[6];
  const float* Uc   = (const float*)d_in[7];
  const float* Uo   = (const float*)d_in[8];
  const float* Wmem = (const float*)d_in[9];
  const float* Umem = (const float*)d_in[10];
  const float* bi   = (const float*)d_in[11];
  const float* bfv  = (const float*)d_in[12];
  const float* bc   = (const float*)d_in[13];
  const float* bo   = (const float*)d_in[14];

  char* ws = (char*)d_ws;
  u32* Upc    = (u32*)(ws);                 // 512 KB
  u32* Wcx    = (u32*)(ws + 524288);        // 256 KB
  u32* WmT    = (u32*)(ws + 786432);        //  32 KB
  u32* UmT    = (u32*)(ws + 819200);        //  32 KB
  float* bias = (float*)(ws + 851968);      //   4 KB
  u32* st     = (u32*)(ws + (1 << 20));     // 256 KB state
  float* X    = (float*)(ws + (2u << 20));  // B*tlen*1024 f32

  int tlen = 1024;
  while (tlen > 64 && (size_t)(2u << 20) + (size_t)BB * tlen * 4096 > ws_size) tlen >>= 1;
  const int nch = TT / tlen;

  pack_kernel<<<256, 256, 0, stream>>>(Wi, Wf, Wc, Wo, Ui, Uf, Uc, Uo, Wmem, Umem,
                                       bi, bfv, bc, bo, Upc, Wcx, WmT, UmT, bias);
  for (int ch = 0; ch < nch; ++ch) {
    int t0 = ch * tlen;
    xproj_kernel<<<2 * tlen, 512, 0, stream>>>(inp, Wcx, bias, X, t0, tlen);
    rec_kernel<<<BB, 256, 0, stream>>>(Upc, WmT, UmT, X, (float*)d_out, st, t0, tlen);
  }
}